// Round 7
// baseline (367.057 us; speedup 1.0000x reference)
//
#include <hip/hip_runtime.h>
#include <hip/hip_bf16.h>
#include <cstdint>
#include <cstddef>

// Problem dims (fixed by reference)
constexpr int NB = 4;
constexpr int NL = 4096;
constexpr int NH = 1024;
constexpr int NU = 1024;
constexpr int NM = NB * NL;        // 16384 rows
constexpr int NCHUNK = 64;
constexpr int CLEN = NL / NCHUNK;  // 64

typedef __bf16 bf16x8 __attribute__((ext_vector_type(8)));
typedef __bf16 bf16x4 __attribute__((ext_vector_type(4)));
typedef float  f32x4  __attribute__((ext_vector_type(4)));

// ---------------- cast fp32 -> bf16 (vectorized) ----------------
__global__ __launch_bounds__(256) void cast_f32_to_bf16(
    const float* __restrict__ in, __bf16* __restrict__ out, int n4) {
  int stride = gridDim.x * 256;
  for (int i = blockIdx.x * 256 + threadIdx.x; i < n4; i += stride) {
    const float4 v = reinterpret_cast<const float4*>(in)[i];
    bf16x4 o;
    o[0] = (__bf16)v.x; o[1] = (__bf16)v.y; o[2] = (__bf16)v.z; o[3] = (__bf16)v.w;
    reinterpret_cast<bf16x4*>(out)[i] = o;
  }
}

// ---------------- transpose + cast: W[K][N] f32 -> Wt[N][K] bf16 ----------------
__global__ __launch_bounds__(256) void transpose_cast(
    const float* __restrict__ W, __bf16* __restrict__ Wt, int K, int N) {
  __shared__ float tile[32][33];
  int tx = threadIdx.x, ty = threadIdx.y;     // block (32,8)
  int n0 = blockIdx.x * 32, k0 = blockIdx.y * 32;
  #pragma unroll
  for (int i = 0; i < 32; i += 8)
    tile[ty + i][tx] = W[(size_t)(k0 + ty + i) * N + n0 + tx];
  __syncthreads();
  #pragma unroll
  for (int i = 0; i < 32; i += 8)
    Wt[(size_t)(n0 + ty + i) * K + k0 + tx] = (__bf16)tile[tx][ty + i];
}

// ================= 256x256 8-phase GEMM (T2+T3+T4+T5) =================
// C = A[M,K](bf16) * Bt[N,K]^T(bf16). BK=64, 8 waves (2M x 4N), 512 thr.
// LDS: 2 bufs x (A 32KB + B 32KB) = 128KB. Stripe = 16KB (one qm/qn slice).
// r7: REVERTED r4's cross-phase fragment reuse — measured A/B: reuse made
// GEMM1 163->194us, MfmaUtil 26.5->21.6% (pure stall add; LDS-read pipe was
// NOT the binder). Back to fresh per-phase reads (12 ds_read_b128/phase).
// Schedule per K-tile t (phases = quadrants):
//   ph1 (qm0,qn0): stage Bs1(t+1)->buf^1   [buf^1 free since t-1 ph4]
//   ph2 (qm1,qn0): stage As1(t+1)->buf^1
//   ph3 (qm0,qn1): stage Bs0(t+2)->buf     [Bs0 last read ph1, 2 barriers ago]
//   ph4 (qm1,qn1): stage As0(t+2)->buf     [As0 last read ph2, 2 barriers ago]
// vmcnt discipline (T4): counted vmcnt requires pinned issue order — every
// phase's loads sit between sched_barrier(0)s.
//   [r3 fix] tail (t>=KT-2): ph3/4 skipped -> newest loads ARE tile t+1's
//            stripes -> drain vmcnt(0).
//   [r5 fix] prologue: SBAR0 between stage calls pins order; prologue drains
//            vmcnt(0) (order-independent). t=0 boundary then matches the
//            steady-state invariant exactly.
// LDS swizzle both-sides: byte ^= (row&7)<<4 (read) + inverse-swizzled
// per-lane GLOBAL source for linear global_load_lds dest (m201 pattern).

#define SBAR0 __builtin_amdgcn_sched_barrier(0)

template<int EPI>
__global__ __launch_bounds__(512, 2) void gemm256(
    const __bf16* __restrict__ A, const __bf16* __restrict__ Bt,
    int M, int N, int K,
    const float* __restrict__ bias,
    __bf16* __restrict__ out_r, __bf16* __restrict__ out_k, __bf16* __restrict__ out_v,
    float* __restrict__ out_f32) {
  __shared__ __attribute__((aligned(16))) __bf16 sA[2][256 * 64];
  __shared__ __attribute__((aligned(16))) __bf16 sB[2][256 * 64];

  const int tid = threadIdx.x;
  const int lane = tid & 63;
  const int w = tid >> 6;            // 0..7
  const int wm = w >> 2, wn = w & 3; // 2 x 4 wave grid

  const int ntn = N >> 8;
  const int nwg = gridDim.x;
  const int bid = blockIdx.x;
  const int cpx = nwg >> 3;          // nwg % 8 == 0 for both GEMMs
  const int swz = (bid & 7) * cpx + (bid >> 3);
  const int mt = swz / ntn, nt = swz % ntn;
  const long m0 = (long)mt * 256;
  const long n0 = (long)nt * 256;
  const int KT = K >> 6;

  // per-lane staging source: row within 8-row unit + inverse-swizzled col byte
  const int srow = lane >> 3;
  const int scol = ((lane & 7) ^ srow) << 4;

  auto stageA = [&](int bi, int qm, int t) {
    if (t >= KT) return;
    #pragma unroll
    for (int j = 0; j < 2; ++j) {
      int u = w * 2 + j;
      int row0 = (u < 8) ? (qm * 64 + u * 8) : (128 + qm * 64 + (u - 8) * 8);
      const char* src = (const char*)A + ((m0 + row0 + srow) * (long)K + (long)t * 64) * 2 + scol;
      __builtin_amdgcn_global_load_lds(
          (const __attribute__((address_space(1))) unsigned int*)src,
          (__attribute__((address_space(3))) unsigned int*)((char*)&sA[bi][0] + row0 * 128),
          16, 0, 0);
    }
  };
  auto stageB = [&](int bi, int qn, int t) {
    if (t >= KT) return;
    #pragma unroll
    for (int j = 0; j < 2; ++j) {
      int u = w * 2 + j;
      int row0 = (u >> 2) * 64 + qn * 32 + (u & 3) * 8;
      const char* src = (const char*)Bt + ((n0 + row0 + srow) * (long)K + (long)t * 64) * 2 + scol;
      __builtin_amdgcn_global_load_lds(
          (const __attribute__((address_space(1))) unsigned int*)src,
          (__attribute__((address_space(3))) unsigned int*)((char*)&sB[bi][0] + row0 * 128),
          16, 0, 0);
    }
  };

  f32x4 acc[8][4];
  #pragma unroll
  for (int i = 0; i < 8; ++i)
    #pragma unroll
    for (int j = 0; j < 4; ++j) acc[i][j] = (f32x4)0.f;

#define PHASE(QM, QN, STAGE_STMT)                                              \
  do {                                                                         \
    bf16x8 av[4][2], bv[2][2];                                                 \
    _Pragma("unroll")                                                          \
    for (int f = 0; f < 4; ++f) {                                              \
      _Pragma("unroll")                                                        \
      for (int ks = 0; ks < 2; ++ks) {                                         \
        int r = wm * 128 + ((QM) * 4 + f) * 16 + (lane & 15);                  \
        int c = ks * 64 + (lane & 48);                                         \
        av[f][ks] = *(const bf16x8*)(sAb + r * 128 + (c ^ ((r & 7) << 4)));    \
      }                                                                        \
    }                                                                          \
    _Pragma("unroll")                                                          \
    for (int g = 0; g < 2; ++g) {                                              \
      _Pragma("unroll")                                                        \
      for (int ks = 0; ks < 2; ++ks) {                                         \
        int r = wn * 64 + ((QN) * 2 + g) * 16 + (lane & 15);                   \
        int c = ks * 64 + (lane & 48);                                         \
        bv[g][ks] = *(const bf16x8*)(sBb + r * 128 + (c ^ ((r & 7) << 4)));    \
      }                                                                        \
    }                                                                          \
    STAGE_STMT;                                                                \
    SBAR0;                                                                     \
    __builtin_amdgcn_s_barrier();                                              \
    SBAR0;                                                                     \
    __builtin_amdgcn_s_setprio(1);                                             \
    _Pragma("unroll")                                                          \
    for (int f = 0; f < 4; ++f) {                                              \
      _Pragma("unroll")                                                        \
      for (int g = 0; g < 2; ++g) {                                            \
        acc[(QM) * 4 + f][(QN) * 2 + g] = __builtin_amdgcn_mfma_f32_16x16x32_bf16( \
            av[f][0], bv[g][0], acc[(QM) * 4 + f][(QN) * 2 + g], 0, 0, 0);     \
        acc[(QM) * 4 + f][(QN) * 2 + g] = __builtin_amdgcn_mfma_f32_16x16x32_bf16( \
            av[f][1], bv[g][1], acc[(QM) * 4 + f][(QN) * 2 + g], 0, 0, 0);     \
      }                                                                        \
    }                                                                          \
    __builtin_amdgcn_s_setprio(0);                                             \
    SBAR0;                                                                     \
  } while (0)

#define EBAR { __builtin_amdgcn_s_barrier(); SBAR0; }

  // prologue: tile0 all 4 stripes + tile1 q0 stripes. SBAR0 between stage
  // calls pins issue order; vmcnt(0) drains ALL (order-independent) [r5 fix].
  stageA(0, 0, 0); SBAR0;
  stageB(0, 0, 0); SBAR0;
  stageA(0, 1, 0); SBAR0;
  stageB(0, 1, 0); SBAR0;
  stageA(1, 0, 1); SBAR0;
  stageB(1, 0, 1); SBAR0;
  asm volatile("s_waitcnt vmcnt(0)" ::: "memory");  // tiles 0 + 1q0 resident
  EBAR;

  for (int t = 0; t < KT; ++t) {
    const int bi = t & 1;
    const char* sAb = (const char*)&sA[bi][0];
    const char* sBb = (const char*)&sB[bi][0];
    PHASE(0, 0, stageB(bi ^ 1, 1, t + 1)); EBAR;
    PHASE(1, 0, stageA(bi ^ 1, 1, t + 1)); EBAR;
    PHASE(0, 1, stageB(bi, 0, t + 2));     EBAR;
    PHASE(1, 1, stageA(bi, 0, t + 2));
    SBAR0;
    // Boundary wait. Steady state (incl. t=0 after prologue drain):
    // vmcnt(4) confirms through q1(t+1) -> tile t+1 resident, keeps
    // q0(t+2) in flight. TAIL (t >= KT-2): ph3/ph4 skipped -> newest
    // loads ARE tile t+1's stripes -> drain fully.  [r3 fix]
    if (t < KT - 2) { asm volatile("s_waitcnt vmcnt(4)" ::: "memory"); }
    else            { asm volatile("s_waitcnt vmcnt(0)" ::: "memory"); }
    EBAR;
  }
#undef PHASE
#undef EBAR

  // epilogue: D frag mapping col=lane&15, row=(lane>>4)*4+rr  [m89-verified]
  float bs[4];
  #pragma unroll
  for (int fn = 0; fn < 4; ++fn)
    bs[fn] = bias[n0 + wn * 64 + fn * 16 + (lane & 15)];

  #pragma unroll
  for (int fm = 0; fm < 8; ++fm) {
    #pragma unroll
    for (int fn = 0; fn < 4; ++fn) {
      #pragma unroll
      for (int rr = 0; rr < 4; ++rr) {
        long row = m0 + wm * 128 + fm * 16 + (lane >> 4) * 4 + rr;
        long col = n0 + wn * 64 + fn * 16 + (lane & 15);
        float val = acc[fm][fn][rr] + bs[fn];
        if constexpr (EPI == 0) {
          int reg = (int)(col >> 10);   // 0: r, 1: k, 2: v
          int u = (int)(col & 1023);
          size_t idx = (size_t)row * NU + u;
          if (reg == 0)      out_r[idx] = (__bf16)(1.f / (1.f + __expf(-val)));
          else if (reg == 1) out_k[idx] = (__bf16)__expf(val);
          else               out_v[idx] = (__bf16)val;
        } else {
          out_f32[(size_t)row * N + col] = val;
        }
      }
    }
  }
}

// ---------------- scan pass 1: per-chunk local scans (start from 0) ----------------
__global__ __launch_bounds__(256) void scan_pass1(
    const __bf16* __restrict__ kbuf, const __bf16* __restrict__ vbuf,
    const float* __restrict__ nu_log,
    float* __restrict__ S1, float* __restrict__ S2) {
  int u = blockIdx.x * 256 + threadIdx.x;
  int c = blockIdx.y;
  int b = blockIdx.z;
  float lam = __expf(-__expf(nu_log[u]));
  size_t base = ((size_t)b * NL + (size_t)c * CLEN) * NU + u;
  float y1 = 0.f, y2 = 0.f;
  #pragma unroll 4
  for (int t = 0; t < CLEN; ++t) {
    float kk = (float)kbuf[base + (size_t)t * NU];
    float vv = (float)vbuf[base + (size_t)t * NU];
    y1 = fmaf(lam, y1, kk * vv);
    y2 = fmaf(lam, y2, kk);
  }
  size_t si = ((size_t)b * NCHUNK + c) * NU + u;
  S1[si] = y1;
  S2[si] = y2;
}

// ---------------- scan combine: sequential over chunk summaries ----------------
__global__ __launch_bounds__(256) void scan_combine(
    const float* __restrict__ S1, const float* __restrict__ S2,
    const float* __restrict__ nu_log,
    float* __restrict__ C1, float* __restrict__ C2) {
  int u = blockIdx.x * 256 + threadIdx.x;
  int b = blockIdx.y;
  float lamCL = __expf(-__expf(nu_log[u]) * (float)CLEN);
  float y1 = 0.f, y2 = 0.f;
  for (int c = 0; c < NCHUNK; ++c) {
    size_t si = ((size_t)b * NCHUNK + c) * NU + u;
    C1[si] = y1;
    C2[si] = y2;
    y1 = fmaf(lamCL, y1, S1[si]);
    y2 = fmaf(lamCL, y2, S2[si]);
  }
}

// ---------------- scan pass 2: apply carry, compute x, store bf16 ----------------
__global__ __launch_bounds__(256) void scan_pass2(
    const __bf16* __restrict__ kbuf, const __bf16* __restrict__ vbuf,
    const __bf16* __restrict__ rbuf,
    const float* __restrict__ C1, const float* __restrict__ C2,
    const float* __restrict__ nu_log, const float* __restrict__ gamma_log,
    __bf16* __restrict__ xbuf) {
  int u = blockIdx.x * 256 + threadIdx.x;
  int c = blockIdx.y;
  int b = blockIdx.z;
  float lam = __expf(-__expf(nu_log[u]));
  float gamma = __expf(nu_log[u] + gamma_log[u]) - 1.f;
  size_t si = ((size_t)b * NCHUNK + c) * NU + u;
  float y1 = C1[si], y2 = C2[si];
  size_t base = ((size_t)b * NL + (size_t)c * CLEN) * NU + u;
  #pragma unroll 4
  for (int t = 0; t < CLEN; ++t) {
    size_t idx = base + (size_t)t * NU;
    float kk = (float)kbuf[idx];
    float vv = (float)vbuf[idx];
    float rr = (float)rbuf[idx];
    float kv = kk * vv;
    y1 = fmaf(lam, y1, kv);
    y2 = fmaf(lam, y2, kk);
    float x = (y1 + gamma * kv) / (y2 + gamma * kk + 1e-6f) * rr;
    xbuf[idx] = (__bf16)x;
  }
}

// ---------------- launch ----------------
extern "C" void kernel_launch(void* const* d_in, const int* in_sizes, int n_in,
                              void* d_out, int out_size, void* d_ws, size_t ws_size,
                              hipStream_t stream) {
  const float* inputs    = (const float*)d_in[0];  // [B,L,H]
  const float* W_rkv     = (const float*)d_in[1];  // [H,3U]
  const float* b_rkv     = (const float*)d_in[2];  // [3U]
  const float* W_o       = (const float*)d_in[3];  // [U,H]
  const float* b_o       = (const float*)d_in[4];  // [H]
  const float* nu_log    = (const float*)d_in[5];  // [U]
  const float* gamma_log = (const float*)d_in[6];  // [U]
  float* out = (float*)d_out;

  char* ws = (char*)d_ws;
  size_t off = 0;
  __bf16* Abuf  = (__bf16*)(ws + off); off += (size_t)NM * NH * 2;        // 32MB (also xbuf)
  __bf16* WrkvT = (__bf16*)(ws + off); off += (size_t)3 * NU * NH * 2;    // 6MB
  __bf16* WoT   = (__bf16*)(ws + off); off += (size_t)NH * NU * 2;        // 2MB
  __bf16* rbuf  = (__bf16*)(ws + off); off += (size_t)NM * NU * 2;        // 32MB
  __bf16* kbuf  = (__bf16*)(ws + off); off += (size_t)NM * NU * 2;        // 32MB
  __bf16* vbuf  = (__bf16*)(ws + off); off += (size_t)NM * NU * 2;        // 32MB
  float*  S1    = (float*)(ws + off);  off += (size_t)NB * NCHUNK * NU * 4;
  float*  S2    = (float*)(ws + off);  off += (size_t)NB * NCHUNK * NU * 4;
  float*  C1    = (float*)(ws + off);  off += (size_t)NB * NCHUNK * NU * 4;
  float*  C2    = (float*)(ws + off);  off += (size_t)NB * NCHUNK * NU * 4;
  __bf16* xbuf  = Abuf;  // alias: Abuf dead after GEMM1, xbuf born in pass2

  // 1. cast inputs to bf16 [16384,1024]
  cast_f32_to_bf16<<<2048, 256, 0, stream>>>(inputs, Abuf, (NM * NH) / 4);

  // 2. transpose+cast weights to [N][K] bf16
  transpose_cast<<<dim3(3 * NU / 32, NH / 32), dim3(32, 8), 0, stream>>>(W_rkv, WrkvT, NH, 3 * NU);
  transpose_cast<<<dim3(NH / 32, NU / 32), dim3(32, 8), 0, stream>>>(W_o, WoT, NU, NH);

  // 3. GEMM1 + activations: writes rbuf(bf16, sigmoid), kbuf(bf16, exp), vbuf(bf16)
  gemm256<0><<<(NM / 256) * (3 * NU / 256), 512, 0, stream>>>(
      Abuf, WrkvT, NM, 3 * NU, NH, b_rkv, rbuf, kbuf, vbuf, nullptr);

  // 4. chunked scan over L (64 chunks of 64 steps)
  scan_pass1<<<dim3(NU / 256, NCHUNK, NB), 256, 0, stream>>>(kbuf, vbuf, nu_log, S1, S2);
  scan_combine<<<dim3(NU / 256, NB), 256, 0, stream>>>(S1, S2, nu_log, C1, C2);
  scan_pass2<<<dim3(NU / 256, NCHUNK, NB), 256, 0, stream>>>(
      kbuf, vbuf, rbuf, C1, C2, nu_log, gamma_log, xbuf);

  // 5. GEMM2 + bias: out = x @ W_o + b_o
  gemm256<1><<<(NM / 256) * (NH / 256), 512, 0, stream>>>(
      xbuf, WoT, NM, NH, NU, b_o, nullptr, nullptr, nullptr, out);
}

// Round 8
// 343.720 us; speedup vs baseline: 1.0679x; 1.0679x over previous
//
#include <hip/hip_runtime.h>
#include <hip/hip_bf16.h>
#include <cstdint>
#include <cstddef>

// Problem dims (fixed by reference)
constexpr int NB = 4;
constexpr int NL = 4096;
constexpr int NH = 1024;
constexpr int NU = 1024;
constexpr int NM = NB * NL;        // 16384 rows
constexpr int NCHUNK = 64;
constexpr int CLEN = NL / NCHUNK;  // 64

typedef __bf16 bf16x8 __attribute__((ext_vector_type(8)));
typedef __bf16 bf16x4 __attribute__((ext_vector_type(4)));
typedef float  f32x4  __attribute__((ext_vector_type(4)));

// ---------------- cast fp32 -> bf16 (vectorized) ----------------
__global__ __launch_bounds__(256) void cast_f32_to_bf16(
    const float* __restrict__ in, __bf16* __restrict__ out, int n4) {
  int stride = gridDim.x * 256;
  for (int i = blockIdx.x * 256 + threadIdx.x; i < n4; i += stride) {
    const float4 v = reinterpret_cast<const float4*>(in)[i];
    bf16x4 o;
    o[0] = (__bf16)v.x; o[1] = (__bf16)v.y; o[2] = (__bf16)v.z; o[3] = (__bf16)v.w;
    reinterpret_cast<bf16x4*>(out)[i] = o;
  }
}

// ---------------- transpose + cast: W[K][N] f32 -> Wt[N][K] bf16 ----------------
__global__ __launch_bounds__(256) void transpose_cast(
    const float* __restrict__ W, __bf16* __restrict__ Wt, int K, int N) {
  __shared__ float tile[32][33];
  int tx = threadIdx.x, ty = threadIdx.y;     // block (32,8)
  int n0 = blockIdx.x * 32, k0 = blockIdx.y * 32;
  #pragma unroll
  for (int i = 0; i < 32; i += 8)
    tile[ty + i][tx] = W[(size_t)(k0 + ty + i) * N + n0 + tx];
  __syncthreads();
  #pragma unroll
  for (int i = 0; i < 32; i += 8)
    Wt[(size_t)(n0 + ty + i) * K + k0 + tx] = (__bf16)tile[tx][ty + i];
}

// ================= 256x256 8-phase GEMM (T2+T3+T4+T5) =================
// C = A[M,K](bf16) * Bt[N,K]^T(bf16). BK=64, 8 waves (2M x 4N), 512 thr.
// LDS: smem[2][2][256*64] = 128KB. [0]=A bufs, [1]=B bufs. Stripe = 16KB.
// FRAGMENT REUSE (r6-measured faster than fresh: 194 vs 210 same-store A/B):
//   ph1 (qm0,qn0): read A0,B0; stage Bs1(t+1)->buf^1
//   ph2 (qm1,qn0): read A1;    stage As1(t+1)->buf^1
//   ph3 (qm0,qn1): read B1;    stage Bs0(t+2)->buf
//   ph4 (qm1,qn1): (no reads)  stage As0(t+2)->buf
// vmcnt discipline (T4): counted vmcnt requires pinned issue order (SBAR0s).
//   [r3 fix] tail (t>=KT-2): drain vmcnt(0).
//   [r5 fix] prologue: SBAR0-pinned stages + vmcnt(0) drain.
// r8: COALESCED EPILOGUE (EPI==0) — r4/r6/r7 matrix isolated the bf16
// scattered short-stores as a ~47us cost (163 f32 vs 210 bf16, same MFMA
// cycles). Fix: activations in f32 -> swizzled ds_write_b16 into the dead
// 128KB staging LDS (one 256x256 bf16 tile) -> barrier -> contiguous
// ds_read_b128 -> global_store_dwordx4 (1KB/wave/instr, full sectors).
// LDS swizzle both-sides: byte ^= (row&7)<<4 (read) + inverse-swizzled
// per-lane GLOBAL source for linear global_load_lds dest (m201 pattern).

#define SBAR0 __builtin_amdgcn_sched_barrier(0)

template<int EPI>
__global__ __launch_bounds__(512, 2) void gemm256(
    const __bf16* __restrict__ A, const __bf16* __restrict__ Bt,
    int M, int N, int K,
    const float* __restrict__ bias,
    __bf16* __restrict__ out_r, __bf16* __restrict__ out_k, __bf16* __restrict__ out_v,
    float* __restrict__ out_f32) {
  __shared__ __attribute__((aligned(16))) __bf16 smem[2][2][256 * 64];

  const int tid = threadIdx.x;
  const int lane = tid & 63;
  const int w = tid >> 6;            // 0..7
  const int wm = w >> 2, wn = w & 3; // 2 x 4 wave grid

  const int ntn = N >> 8;
  const int nwg = gridDim.x;
  const int bid = blockIdx.x;
  const int cpx = nwg >> 3;          // nwg % 8 == 0 for both GEMMs
  const int swz = (bid & 7) * cpx + (bid >> 3);
  const int mt = swz / ntn, nt = swz % ntn;
  const long m0 = (long)mt * 256;
  const long n0 = (long)nt * 256;
  const int KT = K >> 6;

  // per-lane staging source: row within 8-row unit + inverse-swizzled col byte
  const int srow = lane >> 3;
  const int scol = ((lane & 7) ^ srow) << 4;

  auto stageA = [&](int bi, int qm, int t) {
    if (t >= KT) return;
    #pragma unroll
    for (int j = 0; j < 2; ++j) {
      int u = w * 2 + j;
      int row0 = (u < 8) ? (qm * 64 + u * 8) : (128 + qm * 64 + (u - 8) * 8);
      const char* src = (const char*)A + ((m0 + row0 + srow) * (long)K + (long)t * 64) * 2 + scol;
      __builtin_amdgcn_global_load_lds(
          (const __attribute__((address_space(1))) unsigned int*)src,
          (__attribute__((address_space(3))) unsigned int*)((char*)&smem[0][bi][0] + row0 * 128),
          16, 0, 0);
    }
  };
  auto stageB = [&](int bi, int qn, int t) {
    if (t >= KT) return;
    #pragma unroll
    for (int j = 0; j < 2; ++j) {
      int u = w * 2 + j;
      int row0 = (u >> 2) * 64 + qn * 32 + (u & 3) * 8;
      const char* src = (const char*)Bt + ((n0 + row0 + srow) * (long)K + (long)t * 64) * 2 + scol;
      __builtin_amdgcn_global_load_lds(
          (const __attribute__((address_space(1))) unsigned int*)src,
          (__attribute__((address_space(3))) unsigned int*)((char*)&smem[1][bi][0] + row0 * 128),
          16, 0, 0);
    }
  };

  f32x4 acc[8][4];
  #pragma unroll
  for (int i = 0; i < 8; ++i)
    #pragma unroll
    for (int j = 0; j < 4; ++j) acc[i][j] = (f32x4)0.f;

  bf16x8 a0[4][2], a1[4][2], bb[2][2];   // cross-phase fragment cache

#define LDA(DST, QM)                                                           \
  _Pragma("unroll")                                                            \
  for (int f = 0; f < 4; ++f) {                                                \
    _Pragma("unroll")                                                          \
    for (int ks = 0; ks < 2; ++ks) {                                           \
      int r = wm * 128 + ((QM) * 4 + f) * 16 + (lane & 15);                    \
      int c = ks * 64 + (lane & 48);                                           \
      DST[f][ks] = *(const bf16x8*)(sAb + r * 128 + (c ^ ((r & 7) << 4)));     \
    }                                                                          \
  }
#define LDB(DST, QN)                                                           \
  _Pragma("unroll")                                                            \
  for (int g = 0; g < 2; ++g) {                                                \
    _Pragma("unroll")                                                          \
    for (int ks = 0; ks < 2; ++ks) {                                           \
      int r = wn * 64 + ((QN) * 2 + g) * 16 + (lane & 15);                     \
      int c = ks * 64 + (lane & 48);                                           \
      DST[g][ks] = *(const bf16x8*)(sBb + r * 128 + (c ^ ((r & 7) << 4)));     \
    }                                                                          \
  }
#define MFMAQ(QM, QN, AV, BV)                                                  \
  __builtin_amdgcn_s_setprio(1);                                               \
  _Pragma("unroll")                                                            \
  for (int f = 0; f < 4; ++f) {                                                \
    _Pragma("unroll")                                                          \
    for (int g = 0; g < 2; ++g) {                                              \
      acc[(QM) * 4 + f][(QN) * 2 + g] = __builtin_amdgcn_mfma_f32_16x16x32_bf16( \
          AV[f][0], BV[g][0], acc[(QM) * 4 + f][(QN) * 2 + g], 0, 0, 0);       \
      acc[(QM) * 4 + f][(QN) * 2 + g] = __builtin_amdgcn_mfma_f32_16x16x32_bf16( \
          AV[f][1], BV[g][1], acc[(QM) * 4 + f][(QN) * 2 + g], 0, 0, 0);       \
    }                                                                          \
  }                                                                            \
  __builtin_amdgcn_s_setprio(0);
#define PBAR { SBAR0; __builtin_amdgcn_s_barrier(); SBAR0; }
#define EBAR { __builtin_amdgcn_s_barrier(); SBAR0; }

  // prologue: tile0 all 4 stripes + tile1 q0 stripes. SBAR0 between stage
  // calls pins issue order; vmcnt(0) drains ALL (order-independent) [r5 fix].
  stageA(0, 0, 0); SBAR0;
  stageB(0, 0, 0); SBAR0;
  stageA(0, 1, 0); SBAR0;
  stageB(0, 1, 0); SBAR0;
  stageA(1, 0, 1); SBAR0;
  stageB(1, 0, 1); SBAR0;
  asm volatile("s_waitcnt vmcnt(0)" ::: "memory");  // tiles 0 + 1q0 resident
  EBAR;

  for (int t = 0; t < KT; ++t) {
    const int bi = t & 1;
    const char* sAb = (const char*)&smem[0][bi][0];
    const char* sBb = (const char*)&smem[1][bi][0];
    // ph1 (qm0,qn0)
    LDA(a0, 0); LDB(bb, 0); stageB(bi ^ 1, 1, t + 1);
    PBAR; MFMAQ(0, 0, a0, bb); SBAR0; EBAR;
    // ph2 (qm1,qn0) — reuse bb
    LDA(a1, 1); stageA(bi ^ 1, 1, t + 1);
    PBAR; MFMAQ(1, 0, a1, bb); SBAR0; EBAR;
    // ph3 (qm0,qn1) — reuse a0, overwrite bb
    LDB(bb, 1); stageB(bi, 0, t + 2);
    PBAR; MFMAQ(0, 1, a0, bb); SBAR0; EBAR;
    // ph4 (qm1,qn1) — reuse a1, bb; no ds_reads
    stageA(bi, 0, t + 2);
    PBAR; MFMAQ(1, 1, a1, bb); SBAR0;
    SBAR0;
    // Boundary wait: vmcnt(4) steady (q0(t+2) stays in flight);
    // TAIL (t >= KT-2): newest loads ARE tile t+1's -> drain. [r3 fix]
    if (t < KT - 2) { asm volatile("s_waitcnt vmcnt(4)" ::: "memory"); }
    else            { asm volatile("s_waitcnt vmcnt(0)" ::: "memory"); }
    EBAR;
  }
#undef LDA
#undef LDB
#undef MFMAQ
#undef PBAR
#undef EBAR

  // epilogue: D frag mapping col=lane&15, row=(lane>>4)*4+rr  [m89-verified]
  float bs[4];
  #pragma unroll
  for (int fn = 0; fn < 4; ++fn)
    bs[fn] = bias[n0 + wn * 64 + fn * 16 + (lane & 15)];

  if constexpr (EPI == 0) {
    // r8 coalesced epilogue. Tile cols lie in ONE of r/k/v (n0%1024+256<=1024).
    const int reg = (int)(n0 >> 10);          // 0:r 1:k 2:v (block-uniform)
    const int u0  = (int)(n0 & 1023);
    __bf16* dst = (reg == 0) ? out_r : (reg == 1) ? out_k : out_v;
    char* eb = (char*)&smem[0][0][0];         // 256 rows x 512B = 128KB view
    // writer: activation in f32, swizzled ds_write_b16
    #pragma unroll
    for (int fm = 0; fm < 8; ++fm) {
      #pragma unroll
      for (int fn = 0; fn < 4; ++fn) {
        #pragma unroll
        for (int rr = 0; rr < 4; ++rr) {
          int row = wm * 128 + fm * 16 + (lane >> 4) * 4 + rr;
          int col = wn * 64 + fn * 16 + (lane & 15);
          float val = acc[fm][fn][rr] + bs[fn];
          if (reg == 0)      val = 1.f / (1.f + __expf(-val));
          else if (reg == 1) val = __expf(val);
          *(__bf16*)(eb + row * 512 + ((col * 2) ^ ((row & 7) << 4))) = (__bf16)val;
        }
      }
    }
    __syncthreads();
    // reader: contiguous b128 chunks -> coalesced 16B global stores
    #pragma unroll
    for (int i = 0; i < 16; ++i) {
      int chunk = i * 512 + tid;              // 8192 chunks of 16B
      int gr = chunk >> 5;                    // tile row
      int c16 = chunk & 31;                   // 16B chunk within row
      bf16x8 vv = *(const bf16x8*)(eb + gr * 512 + ((c16 * 16) ^ ((gr & 7) << 4)));
      *(bf16x8*)(dst + (m0 + gr) * NU + u0 + c16 * 8) = vv;
    }
  } else {
    #pragma unroll
    for (int fm = 0; fm < 8; ++fm) {
      #pragma unroll
      for (int fn = 0; fn < 4; ++fn) {
        #pragma unroll
        for (int rr = 0; rr < 4; ++rr) {
          long row = m0 + wm * 128 + fm * 16 + (lane >> 4) * 4 + rr;
          long col = n0 + wn * 64 + fn * 16 + (lane & 15);
          out_f32[(size_t)row * N + col] = acc[fm][fn][rr] + bs[fn];
        }
      }
    }
  }
}

// ---------------- scan pass 1: per-chunk local scans (start from 0) ----------------
__global__ __launch_bounds__(256) void scan_pass1(
    const __bf16* __restrict__ kbuf, const __bf16* __restrict__ vbuf,
    const float* __restrict__ nu_log,
    float* __restrict__ S1, float* __restrict__ S2) {
  int u = blockIdx.x * 256 + threadIdx.x;
  int c = blockIdx.y;
  int b = blockIdx.z;
  float lam = __expf(-__expf(nu_log[u]));
  size_t base = ((size_t)b * NL + (size_t)c * CLEN) * NU + u;
  float y1 = 0.f, y2 = 0.f;
  #pragma unroll 4
  for (int t = 0; t < CLEN; ++t) {
    float kk = (float)kbuf[base + (size_t)t * NU];
    float vv = (float)vbuf[base + (size_t)t * NU];
    y1 = fmaf(lam, y1, kk * vv);
    y2 = fmaf(lam, y2, kk);
  }
  size_t si = ((size_t)b * NCHUNK + c) * NU + u;
  S1[si] = y1;
  S2[si] = y2;
}

// ---------------- scan combine: sequential over chunk summaries ----------------
__global__ __launch_bounds__(256) void scan_combine(
    const float* __restrict__ S1, const float* __restrict__ S2,
    const float* __restrict__ nu_log,
    float* __restrict__ C1, float* __restrict__ C2) {
  int u = blockIdx.x * 256 + threadIdx.x;
  int b = blockIdx.y;
  float lamCL = __expf(-__expf(nu_log[u]) * (float)CLEN);
  float y1 = 0.f, y2 = 0.f;
  for (int c = 0; c < NCHUNK; ++c) {
    size_t si = ((size_t)b * NCHUNK + c) * NU + u;
    C1[si] = y1;
    C2[si] = y2;
    y1 = fmaf(lamCL, y1, S1[si]);
    y2 = fmaf(lamCL, y2, S2[si]);
  }
}

// ---------------- scan pass 2: apply carry, compute x, store bf16 ----------------
__global__ __launch_bounds__(256) void scan_pass2(
    const __bf16* __restrict__ kbuf, const __bf16* __restrict__ vbuf,
    const __bf16* __restrict__ rbuf,
    const float* __restrict__ C1, const float* __restrict__ C2,
    const float* __restrict__ nu_log, const float* __restrict__ gamma_log,
    __bf16* __restrict__ xbuf) {
  int u = blockIdx.x * 256 + threadIdx.x;
  int c = blockIdx.y;
  int b = blockIdx.z;
  float lam = __expf(-__expf(nu_log[u]));
  float gamma = __expf(nu_log[u] + gamma_log[u]) - 1.f;
  size_t si = ((size_t)b * NCHUNK + c) * NU + u;
  float y1 = C1[si], y2 = C2[si];
  size_t base = ((size_t)b * NL + (size_t)c * CLEN) * NU + u;
  #pragma unroll 4
  for (int t = 0; t < CLEN; ++t) {
    size_t idx = base + (size_t)t * NU;
    float kk = (float)kbuf[idx];
    float vv = (float)vbuf[idx];
    float rr = (float)rbuf[idx];
    float kv = kk * vv;
    y1 = fmaf(lam, y1, kv);
    y2 = fmaf(lam, y2, kk);
    float x = (y1 + gamma * kv) / (y2 + gamma * kk + 1e-6f) * rr;
    xbuf[idx] = (__bf16)x;
  }
}

// ---------------- launch ----------------
extern "C" void kernel_launch(void* const* d_in, const int* in_sizes, int n_in,
                              void* d_out, int out_size, void* d_ws, size_t ws_size,
                              hipStream_t stream) {
  const float* inputs    = (const float*)d_in[0];  // [B,L,H]
  const float* W_rkv     = (const float*)d_in[1];  // [H,3U]
  const float* b_rkv     = (const float*)d_in[2];  // [3U]
  const float* W_o       = (const float*)d_in[3];  // [U,H]
  const float* b_o       = (const float*)d_in[4];  // [H]
  const float* nu_log    = (const float*)d_in[5];  // [U]
  const float* gamma_log = (const float*)d_in[6];  // [U]
  float* out = (float*)d_out;

  char* ws = (char*)d_ws;
  size_t off = 0;
  __bf16* Abuf  = (__bf16*)(ws + off); off += (size_t)NM * NH * 2;        // 32MB (also xbuf)
  __bf16* WrkvT = (__bf16*)(ws + off); off += (size_t)3 * NU * NH * 2;    // 6MB
  __bf16* WoT   = (__bf16*)(ws + off); off += (size_t)NH * NU * 2;        // 2MB
  __bf16* rbuf  = (__bf16*)(ws + off); off += (size_t)NM * NU * 2;        // 32MB
  __bf16* kbuf  = (__bf16*)(ws + off); off += (size_t)NM * NU * 2;        // 32MB
  __bf16* vbuf  = (__bf16*)(ws + off); off += (size_t)NM * NU * 2;        // 32MB
  float*  S1    = (float*)(ws + off);  off += (size_t)NB * NCHUNK * NU * 4;
  float*  S2    = (float*)(ws + off);  off += (size_t)NB * NCHUNK * NU * 4;
  float*  C1    = (float*)(ws + off);  off += (size_t)NB * NCHUNK * NU * 4;
  float*  C2    = (float*)(ws + off);  off += (size_t)NB * NCHUNK * NU * 4;
  __bf16* xbuf  = Abuf;  // alias: Abuf dead after GEMM1, xbuf born in pass2

  // 1. cast inputs to bf16 [16384,1024]
  cast_f32_to_bf16<<<2048, 256, 0, stream>>>(inputs, Abuf, (NM * NH) / 4);

  // 2. transpose+cast weights to [N][K] bf16
  transpose_cast<<<dim3(3 * NU / 32, NH / 32), dim3(32, 8), 0, stream>>>(W_rkv, WrkvT, NH, 3 * NU);
  transpose_cast<<<dim3(NH / 32, NU / 32), dim3(32, 8), 0, stream>>>(W_o, WoT, NU, NH);

  // 3. GEMM1 + activations: writes rbuf(bf16, sigmoid), kbuf(bf16, exp), vbuf(bf16)
  gemm256<0><<<(NM / 256) * (3 * NU / 256), 512, 0, stream>>>(
      Abuf, WrkvT, NM, 3 * NU, NH, b_rkv, rbuf, kbuf, vbuf, nullptr);

  // 4. chunked scan over L (64 chunks of 64 steps)
  scan_pass1<<<dim3(NU / 256, NCHUNK, NB), 256, 0, stream>>>(kbuf, vbuf, nu_log, S1, S2);
  scan_combine<<<dim3(NU / 256, NB), 256, 0, stream>>>(S1, S2, nu_log, C1, C2);
  scan_pass2<<<dim3(NU / 256, NCHUNK, NB), 256, 0, stream>>>(
      kbuf, vbuf, rbuf, C1, C2, nu_log, gamma_log, xbuf);

  // 5. GEMM2 + bias: out = x @ W_o + b_o
  gemm256<1><<<(NM / 256) * (NH / 256), 512, 0, stream>>>(
      xbuf, WoT, NM, NH, NU, b_o, nullptr, nullptr, nullptr, out);
}

// Round 9
// 339.157 us; speedup vs baseline: 1.0823x; 1.0135x over previous
//
#include <hip/hip_runtime.h>
#include <hip/hip_bf16.h>
#include <cstdint>
#include <cstddef>

// Problem dims (fixed by reference)
constexpr int NB = 4;
constexpr int NL = 4096;
constexpr int NH = 1024;
constexpr int NU = 1024;
constexpr int NM = NB * NL;        // 16384 rows
constexpr int NCHUNK = 64;
constexpr int CLEN = NL / NCHUNK;  // 64

typedef __bf16 bf16x8 __attribute__((ext_vector_type(8)));
typedef __bf16 bf16x4 __attribute__((ext_vector_type(4)));
typedef float  f32x4  __attribute__((ext_vector_type(4)));

// ---------------- cast fp32 -> bf16 (vectorized) ----------------
__global__ __launch_bounds__(256) void cast_f32_to_bf16(
    const float* __restrict__ in, __bf16* __restrict__ out, int n4) {
  int stride = gridDim.x * 256;
  for (int i = blockIdx.x * 256 + threadIdx.x; i < n4; i += stride) {
    const float4 v = reinterpret_cast<const float4*>(in)[i];
    bf16x4 o;
    o[0] = (__bf16)v.x; o[1] = (__bf16)v.y; o[2] = (__bf16)v.z; o[3] = (__bf16)v.w;
    reinterpret_cast<bf16x4*>(out)[i] = o;
  }
}

// ---------------- transpose + cast: W[K][N] f32 -> Wt[N][K] bf16 ----------------
__global__ __launch_bounds__(256) void transpose_cast(
    const float* __restrict__ W, __bf16* __restrict__ Wt, int K, int N) {
  __shared__ float tile[32][33];
  int tx = threadIdx.x, ty = threadIdx.y;     // block (32,8)
  int n0 = blockIdx.x * 32, k0 = blockIdx.y * 32;
  #pragma unroll
  for (int i = 0; i < 32; i += 8)
    tile[ty + i][tx] = W[(size_t)(k0 + ty + i) * N + n0 + tx];
  __syncthreads();
  #pragma unroll
  for (int i = 0; i < 32; i += 8)
    Wt[(size_t)(n0 + ty + i) * K + k0 + tx] = (__bf16)tile[tx][ty + i];
}

// ================= 256x256 2-phase GEMM (T2+T3+T4+T5) =================
// C = A[M,K](bf16) * Bt[N,K]^T(bf16). BK=64, 8 waves (2M x 4N), 512 thr.
// LDS: smem[2][2][256*64] = 128KB. [0]=A bufs, [1]=B bufs. Stripe = 16KB.
// r9: 4 phases -> 2 phases per K-tile (split on qm only). r8 PMC showed
// MfmaUtil 31% with per-phase MFMA 620cyc vs reads 576cyc serialized by 8
// barriers/K-tile lockstep. Merged: per phase 32 MFMA (1240cyc) vs <=16
// ds_read_b128 (192cyc), barriers 8->4/K-tile. Hazards unchanged:
//   phA (qm0 x qn0,qn1): read A0,B0,B1; stage Bs1,As1(t+1)->buf^1
//        [B1^1 last read t-1 phA >=3 bar; A1^1 last read t-1 phB >=1 bar]
//   phB (qm1 x qn0,qn1): read A1 (reuse B); stage Bs0,As0(t+2)->buf
//        [A0/B0 of buf last read phA, lgkm-drained before phA barrier]
// vmcnt (T4): per-phase 4-load groups, order pinned by SBAR0s.
//   Steady: 12 in flight at boundary, vmcnt(4) confirms oldest 8 =
//   q0(t+1)+q1(t+1) -> tile t+1 resident, keeps q0(t+2) in flight.
//   [r3 fix] tail (t>=KT-2): drain vmcnt(0).
//   [r5 fix] prologue: SBAR0-pinned stages + vmcnt(0) drain.
// r8: coalesced EPI==0 epilogue via dead staging LDS (bf16 tile round-trip).
// LDS swizzle both-sides: byte ^= (row&7)<<4 (read) + inverse-swizzled
// per-lane GLOBAL source for linear global_load_lds dest (m201 pattern).

#define SBAR0 __builtin_amdgcn_sched_barrier(0)

template<int EPI>
__global__ __launch_bounds__(512, 2) void gemm256(
    const __bf16* __restrict__ A, const __bf16* __restrict__ Bt,
    int M, int N, int K,
    const float* __restrict__ bias,
    __bf16* __restrict__ out_r, __bf16* __restrict__ out_k, __bf16* __restrict__ out_v,
    float* __restrict__ out_f32) {
  __shared__ __attribute__((aligned(16))) __bf16 smem[2][2][256 * 64];

  const int tid = threadIdx.x;
  const int lane = tid & 63;
  const int w = tid >> 6;            // 0..7
  const int wm = w >> 2, wn = w & 3; // 2 x 4 wave grid

  const int ntn = N >> 8;
  const int nwg = gridDim.x;
  const int bid = blockIdx.x;
  const int cpx = nwg >> 3;          // nwg % 8 == 0 for both GEMMs
  const int swz = (bid & 7) * cpx + (bid >> 3);
  const int mt = swz / ntn, nt = swz % ntn;
  const long m0 = (long)mt * 256;
  const long n0 = (long)nt * 256;
  const int KT = K >> 6;

  // per-lane staging source: row within 8-row unit + inverse-swizzled col byte
  const int srow = lane >> 3;
  const int scol = ((lane & 7) ^ srow) << 4;

  auto stageA = [&](int bi, int qm, int t) {
    if (t >= KT) return;
    #pragma unroll
    for (int j = 0; j < 2; ++j) {
      int u = w * 2 + j;
      int row0 = (u < 8) ? (qm * 64 + u * 8) : (128 + qm * 64 + (u - 8) * 8);
      const char* src = (const char*)A + ((m0 + row0 + srow) * (long)K + (long)t * 64) * 2 + scol;
      __builtin_amdgcn_global_load_lds(
          (const __attribute__((address_space(1))) unsigned int*)src,
          (__attribute__((address_space(3))) unsigned int*)((char*)&smem[0][bi][0] + row0 * 128),
          16, 0, 0);
    }
  };
  auto stageB = [&](int bi, int qn, int t) {
    if (t >= KT) return;
    #pragma unroll
    for (int j = 0; j < 2; ++j) {
      int u = w * 2 + j;
      int row0 = (u >> 2) * 64 + qn * 32 + (u & 3) * 8;
      const char* src = (const char*)Bt + ((n0 + row0 + srow) * (long)K + (long)t * 64) * 2 + scol;
      __builtin_amdgcn_global_load_lds(
          (const __attribute__((address_space(1))) unsigned int*)src,
          (__attribute__((address_space(3))) unsigned int*)((char*)&smem[1][bi][0] + row0 * 128),
          16, 0, 0);
    }
  };

  f32x4 acc[8][4];
  #pragma unroll
  for (int i = 0; i < 8; ++i)
    #pragma unroll
    for (int j = 0; j < 4; ++j) acc[i][j] = (f32x4)0.f;

  bf16x8 a0[4][2], a1[4][2], b0[2][2], b1[2][2];   // cross-phase fragment cache

#define LDA(DST, QM)                                                           \
  _Pragma("unroll")                                                            \
  for (int f = 0; f < 4; ++f) {                                                \
    _Pragma("unroll")                                                          \
    for (int ks = 0; ks < 2; ++ks) {                                           \
      int r = wm * 128 + ((QM) * 4 + f) * 16 + (lane & 15);                    \
      int c = ks * 64 + (lane & 48);                                           \
      DST[f][ks] = *(const bf16x8*)(sAb + r * 128 + (c ^ ((r & 7) << 4)));     \
    }                                                                          \
  }
#define LDB(DST, QN)                                                           \
  _Pragma("unroll")                                                            \
  for (int g = 0; g < 2; ++g) {                                                \
    _Pragma("unroll")                                                          \
    for (int ks = 0; ks < 2; ++ks) {                                           \
      int r = wn * 64 + ((QN) * 2 + g) * 16 + (lane & 15);                     \
      int c = ks * 64 + (lane & 48);                                           \
      DST[g][ks] = *(const bf16x8*)(sBb + r * 128 + (c ^ ((r & 7) << 4)));     \
    }                                                                          \
  }
#define MFMAQ(QM, QN, AV, BV)                                                  \
  _Pragma("unroll")                                                            \
  for (int f = 0; f < 4; ++f) {                                                \
    _Pragma("unroll")                                                          \
    for (int g = 0; g < 2; ++g) {                                              \
      acc[(QM) * 4 + f][(QN) * 2 + g] = __builtin_amdgcn_mfma_f32_16x16x32_bf16( \
          AV[f][0], BV[g][0], acc[(QM) * 4 + f][(QN) * 2 + g], 0, 0, 0);       \
      acc[(QM) * 4 + f][(QN) * 2 + g] = __builtin_amdgcn_mfma_f32_16x16x32_bf16( \
          AV[f][1], BV[g][1], acc[(QM) * 4 + f][(QN) * 2 + g], 0, 0, 0);       \
    }                                                                          \
  }
#define PBAR { SBAR0; __builtin_amdgcn_s_barrier(); SBAR0; }
#define EBAR { __builtin_amdgcn_s_barrier(); SBAR0; }

  // prologue: tile0 all 4 stripes + tile1 q0 stripes. SBAR0 between stage
  // calls pins issue order; vmcnt(0) drains ALL (order-independent) [r5 fix].
  stageA(0, 0, 0); SBAR0;
  stageB(0, 0, 0); SBAR0;
  stageA(0, 1, 0); SBAR0;
  stageB(0, 1, 0); SBAR0;
  stageA(1, 0, 1); SBAR0;
  stageB(1, 0, 1); SBAR0;
  asm volatile("s_waitcnt vmcnt(0)" ::: "memory");  // tiles 0 + 1q0 resident
  EBAR;

  for (int t = 0; t < KT; ++t) {
    const int bi = t & 1;
    const char* sAb = (const char*)&smem[0][bi][0];
    const char* sBb = (const char*)&smem[1][bi][0];
    // phA (qm0 x qn0,qn1)
    LDA(a0, 0); LDB(b0, 0); LDB(b1, 1);
    stageB(bi ^ 1, 1, t + 1); SBAR0;
    stageA(bi ^ 1, 1, t + 1);
    PBAR;
    __builtin_amdgcn_s_setprio(1);
    MFMAQ(0, 0, a0, b0);
    MFMAQ(0, 1, a0, b1);
    __builtin_amdgcn_s_setprio(0);
    SBAR0; EBAR;
    // phB (qm1 x qn0,qn1) — reuse b0,b1
    LDA(a1, 1);
    stageB(bi, 0, t + 2); SBAR0;
    stageA(bi, 0, t + 2);
    PBAR;
    __builtin_amdgcn_s_setprio(1);
    MFMAQ(1, 0, a1, b0);
    MFMAQ(1, 1, a1, b1);
    __builtin_amdgcn_s_setprio(0);
    SBAR0;
    SBAR0;
    // Boundary wait: steady 12 in flight, vmcnt(4) confirms oldest 8 =
    // tile t+1 -> resident, keeps q0(t+2) in flight. TAIL (t >= KT-2):
    // newest loads ARE tile t+1's -> drain.  [r3 fix]
    if (t < KT - 2) { asm volatile("s_waitcnt vmcnt(4)" ::: "memory"); }
    else            { asm volatile("s_waitcnt vmcnt(0)" ::: "memory"); }
    EBAR;
  }
#undef LDA
#undef LDB
#undef MFMAQ
#undef PBAR
#undef EBAR

  // epilogue: D frag mapping col=lane&15, row=(lane>>4)*4+rr  [m89-verified]
  float bs[4];
  #pragma unroll
  for (int fn = 0; fn < 4; ++fn)
    bs[fn] = bias[n0 + wn * 64 + fn * 16 + (lane & 15)];

  if constexpr (EPI == 0) {
    // r8 coalesced epilogue. Tile cols lie in ONE of r/k/v (n0%1024+256<=1024).
    const int reg = (int)(n0 >> 10);          // 0:r 1:k 2:v (block-uniform)
    const int u0  = (int)(n0 & 1023);
    __bf16* dst = (reg == 0) ? out_r : (reg == 1) ? out_k : out_v;
    char* eb = (char*)&smem[0][0][0];         // 256 rows x 512B = 128KB view
    // writer: activation in f32, swizzled ds_write_b16
    #pragma unroll
    for (int fm = 0; fm < 8; ++fm) {
      #pragma unroll
      for (int fn = 0; fn < 4; ++fn) {
        #pragma unroll
        for (int rr = 0; rr < 4; ++rr) {
          int row = wm * 128 + fm * 16 + (lane >> 4) * 4 + rr;
          int col = wn * 64 + fn * 16 + (lane & 15);
          float val = acc[fm][fn][rr] + bs[fn];
          if (reg == 0)      val = 1.f / (1.f + __expf(-val));
          else if (reg == 1) val = __expf(val);
          *(__bf16*)(eb + row * 512 + ((col * 2) ^ ((row & 7) << 4))) = (__bf16)val;
        }
      }
    }
    __syncthreads();
    // reader: contiguous b128 chunks -> coalesced 16B global stores
    #pragma unroll
    for (int i = 0; i < 16; ++i) {
      int chunk = i * 512 + tid;              // 8192 chunks of 16B
      int gr = chunk >> 5;                    // tile row
      int c16 = chunk & 31;                   // 16B chunk within row
      bf16x8 vv = *(const bf16x8*)(eb + gr * 512 + ((c16 * 16) ^ ((gr & 7) << 4)));
      *(bf16x8*)(dst + (m0 + gr) * NU + u0 + c16 * 8) = vv;
    }
  } else {
    #pragma unroll
    for (int fm = 0; fm < 8; ++fm) {
      #pragma unroll
      for (int fn = 0; fn < 4; ++fn) {
        #pragma unroll
        for (int rr = 0; rr < 4; ++rr) {
          long row = m0 + wm * 128 + fm * 16 + (lane >> 4) * 4 + rr;
          long col = n0 + wn * 64 + fn * 16 + (lane & 15);
          out_f32[(size_t)row * N + col] = acc[fm][fn][rr] + bs[fn];
        }
      }
    }
  }
}

// ---------------- scan pass 1: per-chunk local scans (start from 0) ----------------
__global__ __launch_bounds__(256) void scan_pass1(
    const __bf16* __restrict__ kbuf, const __bf16* __restrict__ vbuf,
    const float* __restrict__ nu_log,
    float* __restrict__ S1, float* __restrict__ S2) {
  int u = blockIdx.x * 256 + threadIdx.x;
  int c = blockIdx.y;
  int b = blockIdx.z;
  float lam = __expf(-__expf(nu_log[u]));
  size_t base = ((size_t)b * NL + (size_t)c * CLEN) * NU + u;
  float y1 = 0.f, y2 = 0.f;
  #pragma unroll 4
  for (int t = 0; t < CLEN; ++t) {
    float kk = (float)kbuf[base + (size_t)t * NU];
    float vv = (float)vbuf[base + (size_t)t * NU];
    y1 = fmaf(lam, y1, kk * vv);
    y2 = fmaf(lam, y2, kk);
  }
  size_t si = ((size_t)b * NCHUNK + c) * NU + u;
  S1[si] = y1;
  S2[si] = y2;
}

// ---------------- scan combine: sequential over chunk summaries ----------------
__global__ __launch_bounds__(256) void scan_combine(
    const float* __restrict__ S1, const float* __restrict__ S2,
    const float* __restrict__ nu_log,
    float* __restrict__ C1, float* __restrict__ C2) {
  int u = blockIdx.x * 256 + threadIdx.x;
  int b = blockIdx.y;
  float lamCL = __expf(-__expf(nu_log[u]) * (float)CLEN);
  float y1 = 0.f, y2 = 0.f;
  for (int c = 0; c < NCHUNK; ++c) {
    size_t si = ((size_t)b * NCHUNK + c) * NU + u;
    C1[si] = y1;
    C2[si] = y2;
    y1 = fmaf(lamCL, y1, S1[si]);
    y2 = fmaf(lamCL, y2, S2[si]);
  }
}

// ---------------- scan pass 2: apply carry, compute x, store bf16 ----------------
__global__ __launch_bounds__(256) void scan_pass2(
    const __bf16* __restrict__ kbuf, const __bf16* __restrict__ vbuf,
    const __bf16* __restrict__ rbuf,
    const float* __restrict__ C1, const float* __restrict__ C2,
    const float* __restrict__ nu_log, const float* __restrict__ gamma_log,
    __bf16* __restrict__ xbuf) {
  int u = blockIdx.x * 256 + threadIdx.x;
  int c = blockIdx.y;
  int b = blockIdx.z;
  float lam = __expf(-__expf(nu_log[u]));
  float gamma = __expf(nu_log[u] + gamma_log[u]) - 1.f;
  size_t si = ((size_t)b * NCHUNK + c) * NU + u;
  float y1 = C1[si], y2 = C2[si];
  size_t base = ((size_t)b * NL + (size_t)c * CLEN) * NU + u;
  #pragma unroll 4
  for (int t = 0; t < CLEN; ++t) {
    size_t idx = base + (size_t)t * NU;
    float kk = (float)kbuf[idx];
    float vv = (float)vbuf[idx];
    float rr = (float)rbuf[idx];
    float kv = kk * vv;
    y1 = fmaf(lam, y1, kv);
    y2 = fmaf(lam, y2, kk);
    float x = (y1 + gamma * kv) / (y2 + gamma * kk + 1e-6f) * rr;
    xbuf[idx] = (__bf16)x;
  }
}

// ---------------- launch ----------------
extern "C" void kernel_launch(void* const* d_in, const int* in_sizes, int n_in,
                              void* d_out, int out_size, void* d_ws, size_t ws_size,
                              hipStream_t stream) {
  const float* inputs    = (const float*)d_in[0];  // [B,L,H]
  const float* W_rkv     = (const float*)d_in[1];  // [H,3U]
  const float* b_rkv     = (const float*)d_in[2];  // [3U]
  const float* W_o       = (const float*)d_in[3];  // [U,H]
  const float* b_o       = (const float*)d_in[4];  // [H]
  const float* nu_log    = (const float*)d_in[5];  // [U]
  const float* gamma_log = (const float*)d_in[6];  // [U]
  float* out = (float*)d_out;

  char* ws = (char*)d_ws;
  size_t off = 0;
  __bf16* Abuf  = (__bf16*)(ws + off); off += (size_t)NM * NH * 2;        // 32MB (also xbuf)
  __bf16* WrkvT = (__bf16*)(ws + off); off += (size_t)3 * NU * NH * 2;    // 6MB
  __bf16* WoT   = (__bf16*)(ws + off); off += (size_t)NH * NU * 2;        // 2MB
  __bf16* rbuf  = (__bf16*)(ws + off); off += (size_t)NM * NU * 2;        // 32MB
  __bf16* kbuf  = (__bf16*)(ws + off); off += (size_t)NM * NU * 2;        // 32MB
  __bf16* vbuf  = (__bf16*)(ws + off); off += (size_t)NM * NU * 2;        // 32MB
  float*  S1    = (float*)(ws + off);  off += (size_t)NB * NCHUNK * NU * 4;
  float*  S2    = (float*)(ws + off);  off += (size_t)NB * NCHUNK * NU * 4;
  float*  C1    = (float*)(ws + off);  off += (size_t)NB * NCHUNK * NU * 4;
  float*  C2    = (float*)(ws + off);  off += (size_t)NB * NCHUNK * NU * 4;
  __bf16* xbuf  = Abuf;  // alias: Abuf dead after GEMM1, xbuf born in pass2

  // 1. cast inputs to bf16 [16384,1024]
  cast_f32_to_bf16<<<2048, 256, 0, stream>>>(inputs, Abuf, (NM * NH) / 4);

  // 2. transpose+cast weights to [N][K] bf16
  transpose_cast<<<dim3(3 * NU / 32, NH / 32), dim3(32, 8), 0, stream>>>(W_rkv, WrkvT, NH, 3 * NU);
  transpose_cast<<<dim3(NH / 32, NU / 32), dim3(32, 8), 0, stream>>>(W_o, WoT, NU, NH);

  // 3. GEMM1 + activations: writes rbuf(bf16, sigmoid), kbuf(bf16, exp), vbuf(bf16)
  gemm256<0><<<(NM / 256) * (3 * NU / 256), 512, 0, stream>>>(
      Abuf, WrkvT, NM, 3 * NU, NH, b_rkv, rbuf, kbuf, vbuf, nullptr);

  // 4. chunked scan over L (64 chunks of 64 steps)
  scan_pass1<<<dim3(NU / 256, NCHUNK, NB), 256, 0, stream>>>(kbuf, vbuf, nu_log, S1, S2);
  scan_combine<<<dim3(NU / 256, NB), 256, 0, stream>>>(S1, S2, nu_log, C1, C2);
  scan_pass2<<<dim3(NU / 256, NCHUNK, NB), 256, 0, stream>>>(
      kbuf, vbuf, rbuf, C1, C2, nu_log, gamma_log, xbuf);

  // 5. GEMM2 + bias: out = x @ W_o + b_o
  gemm256<1><<<(NM / 256) * (NH / 256), 512, 0, stream>>>(
      xbuf, WoT, NM, NH, NU, b_o, nullptr, nullptr, nullptr, out);
}